// Round 15
// baseline (58.089 us; speedup 1.0000x reference)
//
#include <hip/hip_runtime.h>
#include <hip/hip_bf16.h>

#define NPIX 9216
#define CIN 64
#define ICH 32
#define LOG2E 1.4426950408889634f

typedef float f32x4 __attribute__((ext_vector_type(4)));
typedef short bf16x8 __attribute__((ext_vector_type(8)));

#if __has_builtin(__builtin_amdgcn_exp2f)
#define EXP2(x) __builtin_amdgcn_exp2f(x)
#else
#define EXP2(x) exp2f(x)
#endif

// async global->LDS, 16B per lane, dest = wave-uniform base + lane*16
#define GLLDS(gp, lp) \
  __builtin_amdgcn_global_load_lds( \
      (const __attribute__((address_space(1))) unsigned int*)(gp), \
      (__attribute__((address_space(3))) unsigned int*)(lp), 16, 0, 0)

static __device__ __forceinline__ unsigned short f2bf(float f) {
  union { float f; unsigned u; } v; v.f = f;
  unsigned u = v.u;
  u = u + 0x7FFFu + ((u >> 16) & 1u);
  return (unsigned short)(u >> 16);
}

// ---------------- Kernel A: three 1x1 projections -> bf16 buffers ----------
// (proven r2-r14; zeroes pacc/pl in-kernel)
__global__ __launch_bounds__(256) void proj_kernel(
    const float* __restrict__ x,
    const float* __restrict__ Wt, const float* __restrict__ bt,
    const float* __restrict__ Wp, const float* __restrict__ bp,
    const float* __restrict__ Wg, const float* __restrict__ bg,
    unsigned short* __restrict__ theta,
    unsigned short* __restrict__ phiT,
    unsigned short* __restrict__ vTs,
    float* __restrict__ zbuf)          // pacc+pl region: 304128 floats
{
  const int sub  = blockIdx.x % 36;
  const int grp  = blockIdx.x / 36;      // 0..11, uniform per block
  const int proj = grp >> 2;
  const int og   = (grp & 3) * 8;
  const int m    = sub * 256 + threadIdx.x;

  // zero the partial buffers (76032 float4s over 110592 threads)
  const int t = blockIdx.x * 256 + threadIdx.x;
  if (t < 76032) {
    const f32x4 z4 = {0.f, 0.f, 0.f, 0.f};
    reinterpret_cast<f32x4*>(zbuf)[t] = z4;
  }

  const float* W; const float* bias;
  if (proj == 0)      { W = Wt; bias = bt; }
  else if (proj == 1) { W = Wp; bias = bp; }
  else                { W = Wg; bias = bg; }

  float acc[8];
#pragma unroll
  for (int o = 0; o < 8; ++o) acc[o] = bias[og + o];
  for (int c = 0; c < CIN; ++c) {
    float xv = x[c * NPIX + m];
#pragma unroll
    for (int o = 0; o < 8; ++o) acc[o] = fmaf(W[(og + o) * CIN + c], xv, acc[o]);
  }

  if (proj == 0) {
#pragma unroll
    for (int o = 0; o < 8; ++o) theta[(og + o) * NPIX + m] = f2bf(acc[o] * LOG2E);
  } else if (proj == 1) {
    union { unsigned short s[8]; bf16x8 v; } pk;
#pragma unroll
    for (int o = 0; o < 8; ++o) pk.s[o] = f2bf(acc[o]);
    *reinterpret_cast<bf16x8*>(phiT + m * ICH + og) = pk.v;
  } else {
#pragma unroll
    for (int o = 0; o < 8; ++o) {
      int n = 288 * (og + o) + (m >> 5);       // V row index (reshape identity)
      int k = n & 31;
      int p = ((k >> 2) & 3) * 8 + ((k >> 4) << 2) + (k & 3);  // nu-inverse
      vTs[(m & 31) * NPIX + (n & ~31) + p] = f2bf(acc[o]);
    }
  }
}

// ---------------- Kernel B: flash attention, LDS-staged, split-K=8 ---------
// EXACT r11 kernel (best measured: 43.6 total). 1152 blocks, 4 waves x 16 q,
// 1152 keys in 9 chunks x 128, double-buffered 32KB LDS, 2-phase loop.
__global__ __launch_bounds__(256) void attn_kernel(
    const unsigned short* __restrict__ theta,
    const unsigned short* __restrict__ phiT,
    const unsigned short* __restrict__ vTs,
    float* __restrict__ pacc, float* __restrict__ pl)
{
  __shared__ __align__(16) unsigned char lds[2][16384];

  const int tid = threadIdx.x;
  const int l   = tid & 63;
  const int w   = tid >> 6;          // 0..3
  const int r16 = l & 15;
  const int g   = l >> 4;
  const int qt    = blockIdx.x >> 3;       // 0..143
  const int split = blockIdx.x & 7;
  const int qbase = qt * 64 + w * 16;
  const int keybase = split * 1152;
  const int cbase = (qt * 5) % 9;          // de-lockstep chunk order (sums commute)

  // Q fragment: lane holds Q[q=qbase+r16][ch 8g..8g+7] (theta pre-scaled LOG2E)
  bf16x8 qf = *reinterpret_cast<const bf16x8*>(theta + (qbase + r16) * ICH + 8 * g);

  f32x4 acc0 = {0.f, 0.f, 0.f, 0.f};
  f32x4 acc1 = {0.f, 0.f, 0.f, 0.f};
  const f32x4 z4 = {0.f, 0.f, 0.f, 0.f};
  float l_run = 0.f;

  // ---- staging: one chunk = 16KB (K 8KB + V 8KB), 4 issues per thread ----
  auto stage = [&](int buf, int cc) {
    unsigned char* Lb = &lds[buf][0];
    const int key0 = keybase + cc * 128;
    if (w < 2) {
      // K: keys j*16..j*16+15 contiguous; ch-slot permuted gp = (l&3)^(k&3)
      const int k  = (l >> 2);                      // key within 16-group
      const int gp = (l & 3) ^ (k & 3);             // stored ch-slot
#pragma unroll
      for (int i = 0; i < 4; ++i) {
        const int j = w * 4 + i;                    // 16-key group 0..7
        GLLDS(phiT + (key0 + j * 16 + k) * ICH + gp * 8, Lb + j * 1024);
      }
    } else {
      // V: rows d (256B each), key-slot permuted slot = (l&15)^(d&7)
#pragma unroll
      for (int i = 0; i < 4; ++i) {
        const int dg = (w - 2) * 4 + i;             // 4-row group 0..7
        const int d  = dg * 4 + (l >> 4);
        const int sl = (l & 15) ^ (d & 7);
        GLLDS(vTs + d * NPIX + key0 + sl * 8, Lb + 8192 + dg * 1024);
      }
    }
  };

  // ---- one 32-key step from LDS (fragment values verbatim r8-r11) ----
  auto step = [&](const unsigned char* Lb, int st) {
    const int kk = st * 32 + r16;
    const int kx = (g ^ (kk & 3)) << 4;             // K read swizzle
    const bf16x8 kf0 = *reinterpret_cast<const bf16x8*>(Lb + kk * 64 + kx);
    const bf16x8 kf1 = *reinterpret_cast<const bf16x8*>(Lb + (kk + 16) * 64 + kx);
    const int sp = ((st * 4 + g) ^ (r16 & 7)) * 16; // V read swizzle
    const bf16x8 vf0 = *reinterpret_cast<const bf16x8*>(Lb + 8192 + r16 * 256 + sp);
    const bf16x8 vf1 = *reinterpret_cast<const bf16x8*>(Lb + 8192 + (16 + r16) * 256 + sp);

    f32x4 cs0 = __builtin_amdgcn_mfma_f32_16x16x32_bf16(kf0, qf, z4, 0, 0, 0);
    f32x4 cs1 = __builtin_amdgcn_mfma_f32_16x16x32_bf16(kf1, qf, z4, 0, 0, 0);

    float p[8]; float psum = 0.f;
#pragma unroll
    for (int j = 0; j < 4; ++j) { p[j] = EXP2(cs0[j]); psum += p[j]; }
#pragma unroll
    for (int j = 0; j < 4; ++j) { p[4 + j] = EXP2(cs1[j]); psum += p[4 + j]; }
    l_run += psum;

    union { unsigned u[4]; bf16x8 v; } pk;
#pragma unroll
    for (int j = 0; j < 4; ++j) {
      asm("v_cvt_pk_bf16_f32 %0, %1, %2" : "=v"(pk.u[j]) : "v"(p[2 * j]), "v"(p[2 * j + 1]));
    }

    acc0 = __builtin_amdgcn_mfma_f32_16x16x32_bf16(pk.v, vf0, acc0, 0, 0, 0);
    acc1 = __builtin_amdgcn_mfma_f32_16x16x32_bf16(pk.v, vf1, acc1, 0, 0, 0);
  };

  // ---- 2-phase double-buffered main loop ----
  stage(0, cbase);
  __syncthreads();                 // compiler drains vmcnt before s_barrier
  int cur = 0;
#pragma unroll 1
  for (int c = 0; c < 9; ++c) {
    if (c + 1 < 9) {
      int cn = cbase + c + 1; if (cn >= 9) cn -= 9;
      stage(cur ^ 1, cn);
    }
    step(&lds[cur][0], 0);
    step(&lds[cur][0], 1);
    step(&lds[cur][0], 2);
    step(&lds[cur][0], 3);
    __syncthreads();               // stage landed + all waves done with cur
    cur ^= 1;
  }

  // ---- epilogue: reduce l over the 4 lane-replicas, atomic-merge splits ----
  l_run += __shfl_xor(l_run, 16);
  l_run += __shfl_xor(l_run, 32);

#pragma unroll
  for (int j = 0; j < 4; ++j) {
    const int q = qbase + 4 * g + j;
    atomicAdd(&pacc[q * ICH + r16],      acc0[j]);
    atomicAdd(&pacc[q * ICH + 16 + r16], acc1[j]);
  }
  if (g == 0) atomicAdd(&pl[qbase + r16], l_run);
}

// ---------------- Kernel C: fused second-softmax + out ---------------------
// Replaces merge_kernel + out_kernel. Identity: out-thread (sub,tid) at
// channel c needs yflat[c*9216 + sub*256 + tid], whose q-row is
// c*288 + sub*8 + (tid>>5) and channel tid&31 — one y element per (thread,c),
// and its 32-channel softmax group == the thread's own 32-lane shuffle group.
// So the second softmax runs fully in-register: yreg[c], no LDS, no sync.
__global__ __launch_bounds__(256) void out_kernel(
    const float* __restrict__ x, const float* __restrict__ Wo,
    const float* __restrict__ bo, const float* __restrict__ pacc,
    const float* __restrict__ pl, float* __restrict__ out)
{
  const int sub = blockIdx.x % 36;
  const int o0  = (blockIdx.x / 36) * 8;   // uniform per block
  const int tid = threadIdx.x;
  const int s   = sub * 256 + tid;

  // ---- phase 1: second softmax, one y element per (thread, c) ----
  float yreg[32];
#pragma unroll
  for (int c = 0; c < 32; ++c) {
    const int q = c * 288 + sub * 8 + (tid >> 5);
    float z  = pacc[c * NPIX + sub * 256 + tid] / pl[q];  // coalesced pacc read
    float zl = z * LOG2E;
    float zm = zl;
#pragma unroll
    for (int k = 1; k < 32; k <<= 1) zm = fmaxf(zm, __shfl_xor(zm, k));
    float e = EXP2(zl - zm);
    float ss = e;
#pragma unroll
    for (int k = 1; k < 32; k <<= 1) ss += __shfl_xor(ss, k);
    yreg[c] = e / ss;
  }

  // ---- phase 2: out = Wo*y + bo + x (yv from registers) ----
  float acc[8];
#pragma unroll
  for (int o = 0; o < 8; ++o) acc[o] = 0.f;
#pragma unroll
  for (int c = 0; c < ICH; ++c) {
    float yv = yreg[c];
#pragma unroll
    for (int o = 0; o < 8; ++o) acc[o] = fmaf(Wo[(o0 + o) * ICH + c], yv, acc[o]);
  }
#pragma unroll
  for (int o = 0; o < 8; ++o) {
    int oc = o0 + o;
    out[oc * NPIX + s] = acc[o] + bo[oc] + x[oc * NPIX + s];
  }
}

extern "C" void kernel_launch(void* const* d_in, const int* in_sizes, int n_in,
                              void* d_out, int out_size, void* d_ws, size_t ws_size,
                              hipStream_t stream) {
  const float* x  = (const float*)d_in[0];
  const float* Wt = (const float*)d_in[1];
  const float* bt = (const float*)d_in[2];
  const float* Wp = (const float*)d_in[3];
  const float* bp = (const float*)d_in[4];
  const float* Wg = (const float*)d_in[5];
  const float* bg = (const float*)d_in[6];
  const float* Wo = (const float*)d_in[7];
  const float* bo = (const float*)d_in[8];
  float* out = (float*)d_out;

  char* ws = (char*)d_ws;
  unsigned short* theta = (unsigned short*)(ws);               // [0, 589824)
  unsigned short* phiT  = (unsigned short*)(ws + 589824);      // [589824, 1179648)
  unsigned short* vTs   = (unsigned short*)(ws + 1179648);     // [1179648, 1769472)
  float* pacc = (float*)(ws + 1769472);                        // [1769472, 2949120)
  float* pl   = (float*)(ws + 2949120);                        // [2949120, 2985984)

  proj_kernel<<<432, 256, 0, stream>>>(x, Wt, bt, Wp, bp, Wg, bg, theta, phiT, vTs, pacc);
  attn_kernel<<<1152, 256, 0, stream>>>(theta, phiT, vTs, pacc, pl);
  out_kernel<<<288, 256, 0, stream>>>(x, Wo, bo, pacc, pl, out);
}

// Round 16
// 43.860 us; speedup vs baseline: 1.3244x; 1.3244x over previous
//
#include <hip/hip_runtime.h>
#include <hip/hip_bf16.h>

#define NPIX 9216
#define CIN 64
#define ICH 32
#define LOG2E 1.4426950408889634f

typedef float f32x4 __attribute__((ext_vector_type(4)));
typedef short bf16x8 __attribute__((ext_vector_type(8)));

#if __has_builtin(__builtin_amdgcn_exp2f)
#define EXP2(x) __builtin_amdgcn_exp2f(x)
#else
#define EXP2(x) exp2f(x)
#endif

// async global->LDS, 16B per lane, dest = wave-uniform base + lane*16
#define GLLDS(gp, lp) \
  __builtin_amdgcn_global_load_lds( \
      (const __attribute__((address_space(1))) unsigned int*)(gp), \
      (__attribute__((address_space(3))) unsigned int*)(lp), 16, 0, 0)

static __device__ __forceinline__ unsigned short f2bf(float f) {
  union { float f; unsigned u; } v; v.f = f;
  unsigned u = v.u;
  u = u + 0x7FFFu + ((u >> 16) & 1u);
  return (unsigned short)(u >> 16);
}

// ---------------- Kernel A: three 1x1 projections -> bf16 buffers ----------
// (proven r2-r15; zeroes pacc/pl in-kernel)
__global__ __launch_bounds__(256) void proj_kernel(
    const float* __restrict__ x,
    const float* __restrict__ Wt, const float* __restrict__ bt,
    const float* __restrict__ Wp, const float* __restrict__ bp,
    const float* __restrict__ Wg, const float* __restrict__ bg,
    unsigned short* __restrict__ theta,
    unsigned short* __restrict__ phiT,
    unsigned short* __restrict__ vTs,
    float* __restrict__ zbuf)          // pacc+pl region: 304128 floats
{
  const int sub  = blockIdx.x % 36;
  const int grp  = blockIdx.x / 36;      // 0..11, uniform per block
  const int proj = grp >> 2;
  const int og   = (grp & 3) * 8;
  const int m    = sub * 256 + threadIdx.x;

  // zero the partial buffers (76032 float4s over 110592 threads)
  const int t = blockIdx.x * 256 + threadIdx.x;
  if (t < 76032) {
    const f32x4 z4 = {0.f, 0.f, 0.f, 0.f};
    reinterpret_cast<f32x4*>(zbuf)[t] = z4;
  }

  const float* W; const float* bias;
  if (proj == 0)      { W = Wt; bias = bt; }
  else if (proj == 1) { W = Wp; bias = bp; }
  else                { W = Wg; bias = bg; }

  float acc[8];
#pragma unroll
  for (int o = 0; o < 8; ++o) acc[o] = bias[og + o];
  for (int c = 0; c < CIN; ++c) {
    float xv = x[c * NPIX + m];
#pragma unroll
    for (int o = 0; o < 8; ++o) acc[o] = fmaf(W[(og + o) * CIN + c], xv, acc[o]);
  }

  if (proj == 0) {
#pragma unroll
    for (int o = 0; o < 8; ++o) theta[(og + o) * NPIX + m] = f2bf(acc[o] * LOG2E);
  } else if (proj == 1) {
    union { unsigned short s[8]; bf16x8 v; } pk;
#pragma unroll
    for (int o = 0; o < 8; ++o) pk.s[o] = f2bf(acc[o]);
    *reinterpret_cast<bf16x8*>(phiT + m * ICH + og) = pk.v;
  } else {
#pragma unroll
    for (int o = 0; o < 8; ++o) {
      int n = 288 * (og + o) + (m >> 5);       // V row index (reshape identity)
      int k = n & 31;
      int p = ((k >> 2) & 3) * 8 + ((k >> 4) << 2) + (k & 3);  // nu-inverse
      vTs[(m & 31) * NPIX + (n & ~31) + p] = f2bf(acc[o]);
    }
  }
}

// ---------------- Kernel B: flash attention, LDS-staged, split-K=8 ---------
// EXACT r11 kernel (best measured: 43.6 total) + T5 s_setprio around the
// compute phase. 1152 blocks, 4 waves x 16 q, 1152 keys in 9 chunks x 128,
// double-buffered 32KB LDS, 2-phase loop. Note: blockIdx%8==split => each
// XCD serves exactly one key-split from its private L2 (accidental T1).
__global__ __launch_bounds__(256) void attn_kernel(
    const unsigned short* __restrict__ theta,
    const unsigned short* __restrict__ phiT,
    const unsigned short* __restrict__ vTs,
    float* __restrict__ pacc, float* __restrict__ pl)
{
  __shared__ __align__(16) unsigned char lds[2][16384];

  const int tid = threadIdx.x;
  const int l   = tid & 63;
  const int w   = tid >> 6;          // 0..3
  const int r16 = l & 15;
  const int g   = l >> 4;
  const int qt    = blockIdx.x >> 3;       // 0..143
  const int split = blockIdx.x & 7;
  const int qbase = qt * 64 + w * 16;
  const int keybase = split * 1152;
  const int cbase = (qt * 5) % 9;          // de-lockstep chunk order (sums commute)

  // Q fragment: lane holds Q[q=qbase+r16][ch 8g..8g+7] (theta pre-scaled LOG2E)
  bf16x8 qf = *reinterpret_cast<const bf16x8*>(theta + (qbase + r16) * ICH + 8 * g);

  f32x4 acc0 = {0.f, 0.f, 0.f, 0.f};
  f32x4 acc1 = {0.f, 0.f, 0.f, 0.f};
  const f32x4 z4 = {0.f, 0.f, 0.f, 0.f};
  float l_run = 0.f;

  // ---- staging: one chunk = 16KB (K 8KB + V 8KB), 4 issues per thread ----
  auto stage = [&](int buf, int cc) {
    unsigned char* Lb = &lds[buf][0];
    const int key0 = keybase + cc * 128;
    if (w < 2) {
      // K: keys j*16..j*16+15 contiguous; ch-slot permuted gp = (l&3)^(k&3)
      const int k  = (l >> 2);                      // key within 16-group
      const int gp = (l & 3) ^ (k & 3);             // stored ch-slot
#pragma unroll
      for (int i = 0; i < 4; ++i) {
        const int j = w * 4 + i;                    // 16-key group 0..7
        GLLDS(phiT + (key0 + j * 16 + k) * ICH + gp * 8, Lb + j * 1024);
      }
    } else {
      // V: rows d (256B each), key-slot permuted slot = (l&15)^(d&7)
#pragma unroll
      for (int i = 0; i < 4; ++i) {
        const int dg = (w - 2) * 4 + i;             // 4-row group 0..7
        const int d  = dg * 4 + (l >> 4);
        const int sl = (l & 15) ^ (d & 7);
        GLLDS(vTs + d * NPIX + key0 + sl * 8, Lb + 8192 + dg * 1024);
      }
    }
  };

  // ---- one 32-key step from LDS (fragment values verbatim r8-r11) ----
  auto step = [&](const unsigned char* Lb, int st) {
    const int kk = st * 32 + r16;
    const int kx = (g ^ (kk & 3)) << 4;             // K read swizzle
    const bf16x8 kf0 = *reinterpret_cast<const bf16x8*>(Lb + kk * 64 + kx);
    const bf16x8 kf1 = *reinterpret_cast<const bf16x8*>(Lb + (kk + 16) * 64 + kx);
    const int sp = ((st * 4 + g) ^ (r16 & 7)) * 16; // V read swizzle
    const bf16x8 vf0 = *reinterpret_cast<const bf16x8*>(Lb + 8192 + r16 * 256 + sp);
    const bf16x8 vf1 = *reinterpret_cast<const bf16x8*>(Lb + 8192 + (16 + r16) * 256 + sp);

    f32x4 cs0 = __builtin_amdgcn_mfma_f32_16x16x32_bf16(kf0, qf, z4, 0, 0, 0);
    f32x4 cs1 = __builtin_amdgcn_mfma_f32_16x16x32_bf16(kf1, qf, z4, 0, 0, 0);

    float p[8]; float psum = 0.f;
#pragma unroll
    for (int j = 0; j < 4; ++j) { p[j] = EXP2(cs0[j]); psum += p[j]; }
#pragma unroll
    for (int j = 0; j < 4; ++j) { p[4 + j] = EXP2(cs1[j]); psum += p[4 + j]; }
    l_run += psum;

    union { unsigned u[4]; bf16x8 v; } pk;
#pragma unroll
    for (int j = 0; j < 4; ++j) {
      asm("v_cvt_pk_bf16_f32 %0, %1, %2" : "=v"(pk.u[j]) : "v"(p[2 * j]), "v"(p[2 * j + 1]));
    }

    acc0 = __builtin_amdgcn_mfma_f32_16x16x32_bf16(pk.v, vf0, acc0, 0, 0, 0);
    acc1 = __builtin_amdgcn_mfma_f32_16x16x32_bf16(pk.v, vf1, acc1, 0, 0, 0);
  };

  // ---- 2-phase double-buffered main loop ----
  stage(0, cbase);
  __syncthreads();                 // compiler drains vmcnt before s_barrier
  int cur = 0;
#pragma unroll 1
  for (int c = 0; c < 9; ++c) {
    if (c + 1 < 9) {
      int cn = cbase + c + 1; if (cn >= 9) cn -= 9;
      stage(cur ^ 1, cn);
    }
    __builtin_amdgcn_s_setprio(1);   // T5: favor compute-phase waves (cross-block
    step(&lds[cur][0], 0);           // arbitration: co-resident blocks are not
    step(&lds[cur][0], 1);           // barrier-synced with each other)
    step(&lds[cur][0], 2);
    step(&lds[cur][0], 3);
    __builtin_amdgcn_s_setprio(0);
    __syncthreads();               // stage landed + all waves done with cur
    cur ^= 1;
  }

  // ---- epilogue: reduce l over the 4 lane-replicas, atomic-merge splits ----
  l_run += __shfl_xor(l_run, 16);
  l_run += __shfl_xor(l_run, 32);

#pragma unroll
  for (int j = 0; j < 4; ++j) {
    const int q = qbase + 4 * g + j;
    atomicAdd(&pacc[q * ICH + r16],      acc0[j]);
    atomicAdd(&pacc[q * ICH + 16 + r16], acc1[j]);
  }
  if (g == 0) atomicAdd(&pl[qbase + r16], l_run);
}

// ---------------- Kernel B2: z = pacc/pl, second softmax over 32 ch --------
// (r11 exact — the fused variant (r15) cost +14us in recomputed shuffles)
__global__ __launch_bounds__(256) void merge_kernel(
    const float* __restrict__ pacc, const float* __restrict__ pl,
    float* __restrict__ ybuf)
{
  const int q  = blockIdx.x * 8 + (threadIdx.x >> 5);
  const int ch = threadIdx.x & 31;

  float z  = pacc[q * ICH + ch] / pl[q];
  float zl = z * LOG2E;
  float zm = zl;
#pragma unroll
  for (int k = 1; k < 32; k <<= 1) zm = fmaxf(zm, __shfl_xor(zm, k));
  float e = EXP2(zl - zm);
  float ss = e;
#pragma unroll
  for (int k = 1; k < 32; k <<= 1) ss += __shfl_xor(ss, k);
  ybuf[q * ICH + ch] = e / ss;
}

// ---------------- Kernel C: out = Wo*y + bo + x ----------------------------
// (unchanged, proven r2-r14)
__global__ __launch_bounds__(256) void out_kernel(
    const float* __restrict__ x, const float* __restrict__ Wo,
    const float* __restrict__ bo, const float* __restrict__ ybuf,
    float* __restrict__ out)
{
  const int sub = blockIdx.x % 36;
  const int o0  = (blockIdx.x / 36) * 8;   // uniform per block
  const int s   = sub * 256 + threadIdx.x;

  float acc[8];
#pragma unroll
  for (int o = 0; o < 8; ++o) acc[o] = 0.f;
  for (int c = 0; c < ICH; ++c) {
    float yv = ybuf[c * NPIX + s];   // flat reinterpretation, like reference
#pragma unroll
    for (int o = 0; o < 8; ++o) acc[o] = fmaf(Wo[(o0 + o) * ICH + c], yv, acc[o]);
  }
#pragma unroll
  for (int o = 0; o < 8; ++o) {
    int oc = o0 + o;
    out[oc * NPIX + s] = acc[o] + bo[oc] + x[oc * NPIX + s];
  }
}

extern "C" void kernel_launch(void* const* d_in, const int* in_sizes, int n_in,
                              void* d_out, int out_size, void* d_ws, size_t ws_size,
                              hipStream_t stream) {
  const float* x  = (const float*)d_in[0];
  const float* Wt = (const float*)d_in[1];
  const float* bt = (const float*)d_in[2];
  const float* Wp = (const float*)d_in[3];
  const float* bp = (const float*)d_in[4];
  const float* Wg = (const float*)d_in[5];
  const float* bg = (const float*)d_in[6];
  const float* Wo = (const float*)d_in[7];
  const float* bo = (const float*)d_in[8];
  float* out = (float*)d_out;

  char* ws = (char*)d_ws;
  unsigned short* theta = (unsigned short*)(ws);               // [0, 589824)
  unsigned short* phiT  = (unsigned short*)(ws + 589824);      // [589824, 1179648)
  unsigned short* vTs   = (unsigned short*)(ws + 1179648);     // [1179648, 1769472)
  float* pacc = (float*)(ws + 1769472);                        // [1769472, 2949120)
  float* pl   = (float*)(ws + 2949120);                        // [2949120, 2985984)
  float* ybuf = (float*)(ws);                                  // overlaps theta/phiT (dead after attn)

  proj_kernel<<<432, 256, 0, stream>>>(x, Wt, bt, Wp, bp, Wg, bg, theta, phiT, vTs, pacc);
  attn_kernel<<<1152, 256, 0, stream>>>(theta, phiT, vTs, pacc, pl);
  merge_kernel<<<1152, 256, 0, stream>>>(pacc, pl, ybuf);
  out_kernel<<<288, 256, 0, stream>>>(x, Wo, bo, ybuf, out);
}

// Round 17
// 43.488 us; speedup vs baseline: 1.3358x; 1.0086x over previous
//
#include <hip/hip_runtime.h>
#include <hip/hip_bf16.h>

#define NPIX 9216
#define CIN 64
#define ICH 32
#define LOG2E 1.4426950408889634f

typedef float f32x4 __attribute__((ext_vector_type(4)));
typedef short bf16x8 __attribute__((ext_vector_type(8)));

#if __has_builtin(__builtin_amdgcn_exp2f)
#define EXP2(x) __builtin_amdgcn_exp2f(x)
#else
#define EXP2(x) exp2f(x)
#endif

// async global->LDS, 16B per lane, dest = wave-uniform base + lane*16
#define GLLDS(gp, lp) \
  __builtin_amdgcn_global_load_lds( \
      (const __attribute__((address_space(1))) unsigned int*)(gp), \
      (__attribute__((address_space(3))) unsigned int*)(lp), 16, 0, 0)

static __device__ __forceinline__ unsigned short f2bf(float f) {
  union { float f; unsigned u; } v; v.f = f;
  unsigned u = v.u;
  u = u + 0x7FFFu + ((u >> 16) & 1u);
  return (unsigned short)(u >> 16);
}

// ---------------- Kernel A: three 1x1 projections -> bf16 buffers ----------
// (proven r2-r16; zeroes pacc/pl in-kernel)
__global__ __launch_bounds__(256) void proj_kernel(
    const float* __restrict__ x,
    const float* __restrict__ Wt, const float* __restrict__ bt,
    const float* __restrict__ Wp, const float* __restrict__ bp,
    const float* __restrict__ Wg, const float* __restrict__ bg,
    unsigned short* __restrict__ theta,
    unsigned short* __restrict__ phiT,
    unsigned short* __restrict__ vTs,
    float* __restrict__ zbuf)          // pacc+pl region: 304128 floats
{
  const int sub  = blockIdx.x % 36;
  const int grp  = blockIdx.x / 36;      // 0..11, uniform per block
  const int proj = grp >> 2;
  const int og   = (grp & 3) * 8;
  const int m    = sub * 256 + threadIdx.x;

  // zero the partial buffers (76032 float4s over 110592 threads)
  const int t = blockIdx.x * 256 + threadIdx.x;
  if (t < 76032) {
    const f32x4 z4 = {0.f, 0.f, 0.f, 0.f};
    reinterpret_cast<f32x4*>(zbuf)[t] = z4;
  }

  const float* W; const float* bias;
  if (proj == 0)      { W = Wt; bias = bt; }
  else if (proj == 1) { W = Wp; bias = bp; }
  else                { W = Wg; bias = bg; }

  float acc[8];
#pragma unroll
  for (int o = 0; o < 8; ++o) acc[o] = bias[og + o];
  for (int c = 0; c < CIN; ++c) {
    float xv = x[c * NPIX + m];
#pragma unroll
    for (int o = 0; o < 8; ++o) acc[o] = fmaf(W[(og + o) * CIN + c], xv, acc[o]);
  }

  if (proj == 0) {
#pragma unroll
    for (int o = 0; o < 8; ++o) theta[(og + o) * NPIX + m] = f2bf(acc[o] * LOG2E);
  } else if (proj == 1) {
    union { unsigned short s[8]; bf16x8 v; } pk;
#pragma unroll
    for (int o = 0; o < 8; ++o) pk.s[o] = f2bf(acc[o]);
    *reinterpret_cast<bf16x8*>(phiT + m * ICH + og) = pk.v;
  } else {
#pragma unroll
    for (int o = 0; o < 8; ++o) {
      int n = 288 * (og + o) + (m >> 5);       // V row index (reshape identity)
      int k = n & 31;
      int p = ((k >> 2) & 3) * 8 + ((k >> 4) << 2) + (k & 3);  // nu-inverse
      vTs[(m & 31) * NPIX + (n & ~31) + p] = f2bf(acc[o]);
    }
  }
}

// ---------------- Kernel B: flash attention, LDS-staged, split-K=16 --------
// Concurrency push: grid 2304 (9 blocks/CU by grid, 8 co-resident = the
// 32-wave/CU cap = 8 waves/SIMD, 1.8x r11) to cover the ~300cy per-step
// dependent chain. Block = 4 waves x 16 q, 576 keys in 9 chunks x 64,
// double-buffered 16KB LDS. Staging + read swizzles verbatim r12 (refcheck
// passed); loop structure verbatim r11; split accumulators (A=step0, B=step1)
// halve the dependent PV-MFMA chain (pure fp-add reorder).
__global__ __launch_bounds__(256) void attn_kernel(
    const unsigned short* __restrict__ theta,
    const unsigned short* __restrict__ phiT,
    const unsigned short* __restrict__ vTs,
    float* __restrict__ pacc, float* __restrict__ pl)
{
  __shared__ __align__(16) unsigned char lds[2][8192];

  const int tid = threadIdx.x;
  const int l   = tid & 63;
  const int w   = tid >> 6;          // 0..3
  const int r16 = l & 15;
  const int g   = l >> 4;
  const int qt    = blockIdx.x >> 4;       // 0..143
  const int split = blockIdx.x & 15;       // 0..15
  const int qbase = qt * 64 + w * 16;
  const int keybase = split * 576;
  const int cbase = (unsigned)(qt * 5 + split) % 9;   // de-lockstep (sums commute)

  // Q fragment: lane holds Q[q=qbase+r16][ch 8g..8g+7] (theta pre-scaled LOG2E)
  bf16x8 qf = *reinterpret_cast<const bf16x8*>(theta + (qbase + r16) * ICH + 8 * g);

  f32x4 accA0 = {0.f, 0.f, 0.f, 0.f}, accA1 = {0.f, 0.f, 0.f, 0.f};
  f32x4 accB0 = {0.f, 0.f, 0.f, 0.f}, accB1 = {0.f, 0.f, 0.f, 0.f};
  const f32x4 z4 = {0.f, 0.f, 0.f, 0.f};
  float l_run = 0.f;

  // ---- staging: one chunk = 8KB (K 4KB + V 4KB), 2 issues/thread ----
  // (verbatim r12, refcheck-passed)
  auto stage = [&](int buf, int cc) {
    unsigned char* Lb = &lds[buf][0];
    const int key0 = keybase + cc * 64;
    if (w < 2) {
      // K: 16-key groups j=0..3 contiguous; ch-slot permuted gp=(l&3)^(k&3)
      const int k  = (l >> 2);
      const int gp = (l & 3) ^ (k & 3);
#pragma unroll
      for (int i = 0; i < 2; ++i) {
        const int j = w * 2 + i;                    // 16-key group 0..3
        GLLDS(phiT + (key0 + j * 16 + k) * ICH + gp * 8, Lb + j * 1024);
      }
    } else {
      // V: rows d (128B each), key-slot permuted sl=(l&7)^(d&7)
#pragma unroll
      for (int i = 0; i < 2; ++i) {
        const int dg = (w - 2) * 2 + i;             // 8-row group 0..3
        const int d  = dg * 8 + (l >> 3);
        const int sl = (l & 7) ^ (d & 7);
        GLLDS(vTs + d * NPIX + key0 + sl * 8, Lb + 4096 + dg * 1024);
      }
    }
  };

  // ---- one 32-key step from LDS (read swizzles verbatim r12) ----
  auto step = [&](const unsigned char* Lb, int st, f32x4& a0, f32x4& a1) {
    const int kk = st * 32 + r16;
    const int kx = (g ^ (kk & 3)) << 4;             // K read swizzle
    const bf16x8 kf0 = *reinterpret_cast<const bf16x8*>(Lb + kk * 64 + kx);
    const bf16x8 kf1 = *reinterpret_cast<const bf16x8*>(Lb + (kk + 16) * 64 + kx);
    const int sp = ((st * 4 + g) ^ (r16 & 7)) * 16; // V read swizzle
    const bf16x8 vf0 = *reinterpret_cast<const bf16x8*>(Lb + 4096 + r16 * 128 + sp);
    const bf16x8 vf1 = *reinterpret_cast<const bf16x8*>(Lb + 4096 + (16 + r16) * 128 + sp);

    f32x4 cs0 = __builtin_amdgcn_mfma_f32_16x16x32_bf16(kf0, qf, z4, 0, 0, 0);
    f32x4 cs1 = __builtin_amdgcn_mfma_f32_16x16x32_bf16(kf1, qf, z4, 0, 0, 0);

    float p[8]; float psum = 0.f;
#pragma unroll
    for (int j = 0; j < 4; ++j) { p[j] = EXP2(cs0[j]); psum += p[j]; }
#pragma unroll
    for (int j = 0; j < 4; ++j) { p[4 + j] = EXP2(cs1[j]); psum += p[4 + j]; }
    l_run += psum;

    union { unsigned u[4]; bf16x8 v; } pk;
#pragma unroll
    for (int j = 0; j < 4; ++j) {
      asm("v_cvt_pk_bf16_f32 %0, %1, %2" : "=v"(pk.u[j]) : "v"(p[2 * j]), "v"(p[2 * j + 1]));
    }

    a0 = __builtin_amdgcn_mfma_f32_16x16x32_bf16(pk.v, vf0, a0, 0, 0, 0);
    a1 = __builtin_amdgcn_mfma_f32_16x16x32_bf16(pk.v, vf1, a1, 0, 0, 0);
  };

  // ---- 2-phase double-buffered main loop (r11 structure) ----
  stage(0, cbase);
  __syncthreads();                 // compiler drains vmcnt before s_barrier
  int cur = 0;
#pragma unroll 1
  for (int c = 0; c < 9; ++c) {
    if (c + 1 < 9) {
      int cn = cbase + c + 1; if (cn >= 9) cn -= 9;
      stage(cur ^ 1, cn);
    }
    step(&lds[cur][0], 0, accA0, accA1);   // independent acc chains A/B
    step(&lds[cur][0], 1, accB0, accB1);
    __syncthreads();               // stage landed + all waves done with cur
    cur ^= 1;
  }

  f32x4 acc0 = accA0 + accB0;
  f32x4 acc1 = accA1 + accB1;

  // ---- epilogue: reduce l over the 4 lane-replicas, atomic-merge splits ----
  l_run += __shfl_xor(l_run, 16);
  l_run += __shfl_xor(l_run, 32);

#pragma unroll
  for (int j = 0; j < 4; ++j) {
    const int q = qbase + 4 * g + j;
    atomicAdd(&pacc[q * ICH + r16],      acc0[j]);
    atomicAdd(&pacc[q * ICH + 16 + r16], acc1[j]);
  }
  if (g == 0) atomicAdd(&pl[qbase + r16], l_run);
}

// ---------------- Kernel B2: z = pacc/pl, second softmax over 32 ch --------
// (r11 exact)
__global__ __launch_bounds__(256) void merge_kernel(
    const float* __restrict__ pacc, const float* __restrict__ pl,
    float* __restrict__ ybuf)
{
  const int q  = blockIdx.x * 8 + (threadIdx.x >> 5);
  const int ch = threadIdx.x & 31;

  float z  = pacc[q * ICH + ch] / pl[q];
  float zl = z * LOG2E;
  float zm = zl;
#pragma unroll
  for (int k = 1; k < 32; k <<= 1) zm = fmaxf(zm, __shfl_xor(zm, k));
  float e = EXP2(zl - zm);
  float ss = e;
#pragma unroll
  for (int k = 1; k < 32; k <<= 1) ss += __shfl_xor(ss, k);
  ybuf[q * ICH + ch] = e / ss;
}

// ---------------- Kernel C: out = Wo*y + bo + x ----------------------------
// (unchanged, proven r2-r16)
__global__ __launch_bounds__(256) void out_kernel(
    const float* __restrict__ x, const float* __restrict__ Wo,
    const float* __restrict__ bo, const float* __restrict__ ybuf,
    float* __restrict__ out)
{
  const int sub = blockIdx.x % 36;
  const int o0  = (blockIdx.x / 36) * 8;   // uniform per block
  const int s   = sub * 256 + threadIdx.x;

  float acc[8];
#pragma unroll
  for (int o = 0; o < 8; ++o) acc[o] = 0.f;
  for (int c = 0; c < ICH; ++c) {
    float yv = ybuf[c * NPIX + s];   // flat reinterpretation, like reference
#pragma unroll
    for (int o = 0; o < 8; ++o) acc[o] = fmaf(Wo[(o0 + o) * ICH + c], yv, acc[o]);
  }
#pragma unroll
  for (int o = 0; o < 8; ++o) {
    int oc = o0 + o;
    out[oc * NPIX + s] = acc[o] + bo[oc] + x[oc * NPIX + s];
  }
}

extern "C" void kernel_launch(void* const* d_in, const int* in_sizes, int n_in,
                              void* d_out, int out_size, void* d_ws, size_t ws_size,
                              hipStream_t stream) {
  const float* x  = (const float*)d_in[0];
  const float* Wt = (const float*)d_in[1];
  const float* bt = (const float*)d_in[2];
  const float* Wp = (const float*)d_in[3];
  const float* bp = (const float*)d_in[4];
  const float* Wg = (const float*)d_in[5];
  const float* bg = (const float*)d_in[6];
  const float* Wo = (const float*)d_in[7];
  const float* bo = (const float*)d_in[8];
  float* out = (float*)d_out;

  char* ws = (char*)d_ws;
  unsigned short* theta = (unsigned short*)(ws);               // [0, 589824)
  unsigned short* phiT  = (unsigned short*)(ws + 589824);      // [589824, 1179648)
  unsigned short* vTs   = (unsigned short*)(ws + 1179648);     // [1179648, 1769472)
  float* pacc = (float*)(ws + 1769472);                        // [1769472, 2949120)
  float* pl   = (float*)(ws + 2949120);                        // [2949120, 2985984)
  float* ybuf = (float*)(ws);                                  // overlaps theta/phiT (dead after attn)

  proj_kernel<<<432, 256, 0, stream>>>(x, Wt, bt, Wp, bp, Wg, bg, theta, phiT, vTs, pacc);
  attn_kernel<<<2304, 256, 0, stream>>>(theta, phiT, vTs, pacc, pl);
  merge_kernel<<<1152, 256, 0, stream>>>(pacc, pl, ybuf);
  out_kernel<<<288, 256, 0, stream>>>(x, Wo, bo, ybuf, out);
}